// Round 5
// baseline (315.591 us; speedup 1.0000x reference)
//
#include <hip/hip_runtime.h>

typedef unsigned short u16;
typedef _Float16 f16x8 __attribute__((ext_vector_type(8)));
typedef float f32x4 __attribute__((ext_vector_type(4)));
typedef unsigned int u32x4 __attribute__((ext_vector_type(4)));

#define NB 8
#define NN 2048
#define ND 512
#define NHC 128
#define MTOT (NB*NN)      // 16384
#define CCH 768           // HC + HC + D

__device__ inline u16 f2h(float f) {
  _Float16 h = (_Float16)f;
  return __builtin_bit_cast(u16, h);
}

__device__ inline void gld_lds16(const void* g, void* l) {
  __builtin_amdgcn_global_load_lds(
      (__attribute__((address_space(1))) unsigned int*)(g),
      (__attribute__((address_space(3))) unsigned int*)(l), 16, 0, 0);
}

// ---------------- convert / assemble ----------------

__global__ void cvt_f32_f16(const float* __restrict__ in, u16* __restrict__ out, size_t n4) {
  size_t i = (size_t)blockIdx.x * 256 + threadIdx.x;
  if (i >= n4) return;
  float4 v = ((const float4*)in)[i];
  ushort4 o;
  o.x = f2h(v.x); o.y = f2h(v.y); o.z = f2h(v.z); o.w = f2h(v.w);
  ((ushort4*)out)[i] = o;
}

__global__ void assemble_w(const float* __restrict__ W1, const float* __restrict__ W2,
                           const float* __restrict__ W3, const float* __restrict__ b1,
                           const float* __restrict__ b2, const float* __restrict__ b3,
                           u16* __restrict__ Wcat, float* __restrict__ bcat) {
  int i = blockIdx.x * 256 + threadIdx.x;       // float4 groups: 768*512/4 = 98304
  if (i < 98304) {
    int e = i * 4;
    int rowc = e >> 9;
    int col  = e & 511;
    const float* src = rowc < 128 ? &W1[rowc * 512 + col]
                     : rowc < 256 ? &W2[(rowc - 128) * 512 + col]
                                  : &W3[(rowc - 256) * 512 + col];
    float4 v = *(const float4*)src;
    ushort4 o;
    o.x = f2h(v.x); o.y = f2h(v.y); o.z = f2h(v.z); o.w = f2h(v.w);
    *(ushort4*)&Wcat[e] = o;
  }
  if (i < 768) {
    bcat[i] = i < 128 ? b1[i] : i < 256 ? b2[i - 128] : b3[i - 256];
  }
}

// ---------------- GEMM (C[m,n] = sum_k A[m,k]*B[n,k]), m97 structure, fp16 ----------------

enum { EPI_NONE = 0, EPI_BIAS_LEAKY = 1, EPI_RESID = 2 };

template <int EPI>
__global__ __launch_bounds__(256)
void gemm_bt(const u16* __restrict__ A, const u16* __restrict__ B,
             float* __restrict__ C, int N, int K,
             size_t sA, size_t sB, size_t sC,
             const float* __restrict__ bias, const float* __restrict__ resid) {
  const int bz = blockIdx.z;
  A += (size_t)bz * sA;
  B += (size_t)bz * sB;
  C += (size_t)bz * sC;
  const int row0 = blockIdx.x * 128, col0 = blockIdx.y * 128;
  __shared__ u16 As[128 * 64];
  __shared__ u16 Bs[128 * 64];
  const int tid  = threadIdx.x;
  const int lane = tid & 63;
  const int wave = tid >> 6;
  const int wr = (wave >> 1) * 64, wc = (wave & 1) * 64;
  const int lr  = lane & 15;
  const int lk8 = (lane >> 4) * 8;
  f32x4 acc[4][4] = {};
  for (int kt = 0; kt < K; kt += 64) {
#pragma unroll
    for (int i = 0; i < 4; ++i) {
      int e = i * 256 + tid;
      int r = e >> 3, kc = (e & 7) * 8;
      gld_lds16(A + (size_t)(row0 + r) * K + kt + kc, As + e * 8);
    }
#pragma unroll
    for (int i = 0; i < 4; ++i) {
      int e = i * 256 + tid;
      int r = e >> 3, kc = (e & 7) * 8;
      gld_lds16(B + (size_t)(col0 + r) * K + kt + kc, Bs + e * 8);
    }
    __syncthreads();
#pragma unroll
    for (int kk = 0; kk < 2; ++kk) {
      f16x8 af[4], bg[4];
      const int ko = kk * 32 + lk8;
#pragma unroll
      for (int m = 0; m < 4; ++m)
        af[m] = __builtin_bit_cast(f16x8, *(const u32x4*)&As[(wr + m * 16 + lr) * 64 + ko]);
#pragma unroll
      for (int n = 0; n < 4; ++n)
        bg[n] = __builtin_bit_cast(f16x8, *(const u32x4*)&Bs[(wc + n * 16 + lr) * 64 + ko]);
#pragma unroll
      for (int m = 0; m < 4; ++m)
#pragma unroll
        for (int n = 0; n < 4; ++n)
          acc[m][n] = __builtin_amdgcn_mfma_f32_16x16x32_f16(af[m], bg[n], acc[m][n], 0, 0, 0);
    }
    __syncthreads();
  }
  const int lq4 = (lane >> 4) * 4;
#pragma unroll
  for (int m = 0; m < 4; ++m) {
#pragma unroll
    for (int n = 0; n < 4; ++n) {
      const int col = col0 + wc + n * 16 + lr;
#pragma unroll
      for (int r = 0; r < 4; ++r) {
        const int row = row0 + wr + m * 16 + lq4 + r;
        float v = acc[m][n][r];
        if (EPI == EPI_BIAS_LEAKY) { v += bias[col]; v = v >= 0.0f ? v : 0.01f * v; }
        if (EPI == EPI_RESID)      { v += resid[(size_t)bz * sC + (size_t)row * N + col]; }
        C[(size_t)row * N + col] = v;
      }
    }
  }
}

// ---------------- BatchNorm stats / apply ----------------

__global__ void bn_stats(const float* __restrict__ Y, float* __restrict__ sums) {
  // grid 128 blocks; block handles 128 rows; thread t owns channels 3t..3t+2
  int t = threadIdx.x;
  int c = 3 * t;
  const float* p = Y + (size_t)blockIdx.x * 128 * CCH + c;
  float s0 = 0, s1 = 0, s2 = 0, q0 = 0, q1 = 0, q2 = 0;
  for (int r = 0; r < 128; ++r) {
    float a = p[0], b = p[1], cc = p[2];
    s0 += a; s1 += b; s2 += cc;
    q0 += a * a; q1 += b * b; q2 += cc * cc;
    p += CCH;
  }
  atomicAdd(&sums[c], s0);       atomicAdd(&sums[c + 1], s1);       atomicAdd(&sums[c + 2], s2);
  atomicAdd(&sums[CCH + c], q0); atomicAdd(&sums[CCH + c + 1], q1); atomicAdd(&sums[CCH + c + 2], q2);
}

__global__ void bn_finalize(const float* __restrict__ sums,
                            const float* __restrict__ g1, const float* __restrict__ be1,
                            const float* __restrict__ g2, const float* __restrict__ be2,
                            const float* __restrict__ g3, const float* __restrict__ be3,
                            float* __restrict__ scale, float* __restrict__ shift) {
  int c = blockIdx.x * 256 + threadIdx.x;
  if (c >= CCH) return;
  const float inv = 1.0f / (float)MTOT;
  float mu  = sums[c] * inv;
  float var = sums[CCH + c] * inv - mu * mu;
  float g, be;
  if (c < 128)      { g = g1[c];       be = be1[c]; }
  else if (c < 256) { g = g2[c - 128]; be = be2[c - 128]; }
  else              { g = g3[c - 256]; be = be3[c - 256]; }
  float sc = rsqrtf(var + 1e-5f) * g;
  scale[c] = sc;
  shift[c] = be - mu * sc;
}

__global__ void bn_apply_route(const float* __restrict__ Y, const float* __restrict__ scale,
                               const float* __restrict__ shift, u16* __restrict__ X1b,
                               u16* __restrict__ X2b, u16* __restrict__ X3b) {
  size_t idx4 = (size_t)blockIdx.x * 256 + threadIdx.x;   // 16384*192 total
  int row = (int)(idx4 / 192);
  int c4  = (int)(idx4 % 192);
  int c   = c4 * 4;
  float4 v  = ((const float4*)Y)[idx4];
  float4 sc = ((const float4*)scale)[c4];
  float4 sh = ((const float4*)shift)[c4];
  ushort4 o;
  o.x = f2h(v.x * sc.x + sh.x);
  o.y = f2h(v.y * sc.y + sh.y);
  o.z = f2h(v.z * sc.z + sh.z);
  o.w = f2h(v.w * sc.w + sh.w);
  if (c < 128)      *(ushort4*)&X1b[(size_t)row * 128 + c] = o;
  else if (c < 256) *(ushort4*)&X2b[(size_t)row * 128 + (c - 128)] = o;
  else              *(ushort4*)&X3b[(size_t)row * 512 + (c - 256)] = o;
}

// ---------------- transposes ----------------

__global__ void transpose_f16(const u16* __restrict__ in, u16* __restrict__ out, int R, int C) {
  // per-batch [R][C] -> [C][R]; 64x64 tiles
  __shared__ u16 tile[64][66];
  int bz = blockIdx.z;
  const u16* ib = in + (size_t)bz * R * C;
  u16* ob = out + (size_t)bz * R * C;
  int r0 = blockIdx.x * 64, c0 = blockIdx.y * 64;
  int t = threadIdx.x, tr = t >> 4, tc4 = (t & 15) * 4;
#pragma unroll
  for (int i = 0; i < 4; ++i) {
    int rl = i * 16 + tr;
    ushort4 v = *(const ushort4*)&ib[(size_t)(r0 + rl) * C + c0 + tc4];
    tile[tc4 + 0][rl] = v.x; tile[tc4 + 1][rl] = v.y;
    tile[tc4 + 2][rl] = v.z; tile[tc4 + 3][rl] = v.w;
  }
  __syncthreads();
#pragma unroll
  for (int i = 0; i < 4; ++i) {
    int cl = i * 16 + tr;
    ushort4 o;
    o.x = tile[cl][tc4 + 0]; o.y = tile[cl][tc4 + 1];
    o.z = tile[cl][tc4 + 2]; o.w = tile[cl][tc4 + 3];
    *(ushort4*)&ob[(size_t)(c0 + cl) * R + r0 + tc4] = o;
  }
}

__global__ void row_stats(const float* __restrict__ S, float* __restrict__ Mrow,
                          float* __restrict__ Zrow) {
  // one block per row of S (16384 rows x 2048 cols)
  int row = blockIdx.x;
  const float* r = S + (size_t)row * 2048;
  int t = threadIdx.x;
  float4 v0 = ((const float4*)r)[t];
  float4 v1 = ((const float4*)r)[t + 256];
  float mx = fmaxf(fmaxf(fmaxf(v0.x, v0.y), fmaxf(v0.z, v0.w)),
                   fmaxf(fmaxf(v1.x, v1.y), fmaxf(v1.z, v1.w)));
#pragma unroll
  for (int off = 32; off; off >>= 1) mx = fmaxf(mx, __shfl_xor(mx, off));
  __shared__ float sm[4], szs[4];
  int wave = t >> 6, lane = t & 63;
  if (lane == 0) sm[wave] = mx;
  __syncthreads();
  mx = fmaxf(fmaxf(sm[0], sm[1]), fmaxf(sm[2], sm[3]));
  float s = __expf(v0.x - mx) + __expf(v0.y - mx) + __expf(v0.z - mx) + __expf(v0.w - mx)
          + __expf(v1.x - mx) + __expf(v1.y - mx) + __expf(v1.z - mx) + __expf(v1.w - mx);
#pragma unroll
  for (int off = 32; off; off >>= 1) s += __shfl_xor(s, off);
  if (lane == 0) szs[wave] = s;
  __syncthreads();
  if (t == 0) { Mrow[row] = mx; Zrow[row] = szs[0] + szs[1] + szs[2] + szs[3]; }
}

__global__ void softmax_transpose(const float* __restrict__ S, const float* __restrict__ Mrow,
                                  const float* __restrict__ Zrow, u16* __restrict__ PT) {
  // P[m][n] = exp(S[m][n]-M[m])/Z[m]; write PT[n][m]; 64x64 tiles per batch
  __shared__ u16 tile[64][66];
  int bz = blockIdx.z;
  const float* Sb = S + (size_t)bz * 2048 * 2048;
  u16* PTb = PT + (size_t)bz * 2048 * 2048;
  int m0 = blockIdx.x * 64, n0 = blockIdx.y * 64;
  int t = threadIdx.x, tm = t >> 4, tn4 = (t & 15) * 4;
#pragma unroll
  for (int i = 0; i < 4; ++i) {
    int ml = i * 16 + tm;
    int m = m0 + ml;
    float4 v = *(const float4*)&Sb[(size_t)m * 2048 + n0 + tn4];
    float mm = Mrow[bz * 2048 + m];
    float iz = 1.0f / Zrow[bz * 2048 + m];
    tile[tn4 + 0][ml] = f2h(__expf(v.x - mm) * iz);
    tile[tn4 + 1][ml] = f2h(__expf(v.y - mm) * iz);
    tile[tn4 + 2][ml] = f2h(__expf(v.z - mm) * iz);
    tile[tn4 + 3][ml] = f2h(__expf(v.w - mm) * iz);
  }
  __syncthreads();
#pragma unroll
  for (int i = 0; i < 4; ++i) {
    int nl = i * 16 + tm;
    ushort4 o;
    o.x = tile[nl][tn4 + 0]; o.y = tile[nl][tn4 + 1];
    o.z = tile[nl][tn4 + 2]; o.w = tile[nl][tn4 + 3];
    *(ushort4*)&PTb[(size_t)(n0 + nl) * 2048 + m0 + tn4] = o;
  }
}

// ---------------- launch ----------------

extern "C" void kernel_launch(void* const* d_in, const int* in_sizes, int n_in,
                              void* d_out, int out_size, void* d_ws, size_t ws_size,
                              hipStream_t stream) {
  const float* X   = (const float*)d_in[0];
  const float* W1  = (const float*)d_in[1];
  const float* b1  = (const float*)d_in[2];
  const float* g1  = (const float*)d_in[3];
  const float* be1 = (const float*)d_in[4];
  const float* W2  = (const float*)d_in[5];
  const float* b2  = (const float*)d_in[6];
  const float* g2  = (const float*)d_in[7];
  const float* be2 = (const float*)d_in[8];
  const float* W3  = (const float*)d_in[9];
  const float* b3  = (const float*)d_in[10];
  const float* g3  = (const float*)d_in[11];
  const float* be3 = (const float*)d_in[12];
  float* out = (float*)d_out;

  char* ws = (char*)d_ws;
  // small region
  float* sums  = (float*)ws;                 // 1536
  float* scale = sums + 1536;                // 768
  float* shift = scale + 768;                // 768
  float* bcat  = shift + 768;                // 768
  float* Mrow  = bcat + 768;                 // 16384
  float* Zrow  = Mrow + 16384;               // 16384
  size_t off = (size_t)(1536 + 768 + 768 + 768 + 16384 + 16384) * 4;   // 146432, 256-aligned
  // persistent fp16 region
  u16* X1b = (u16*)(ws + off); off += (size_t)MTOT * 128 * 2;
  u16* X2b = (u16*)(ws + off); off += (size_t)MTOT * 128 * 2;
  u16* X3b = (u16*)(ws + off); off += (size_t)MTOT * 512 * 2;
  u16* X3T = (u16*)(ws + off); off += (size_t)MTOT * 512 * 2;
  u16* PT  = (u16*)(ws + off); off += (size_t)NB * 2048 * 2048 * 2;
  // union region: {Xb, Wcat, Y} (dead before S is written) overlaid with S
  char* uni = ws + off;
  u16*   Xb   = (u16*)uni;                                   // 16 MB
  u16*   Wcat = (u16*)(uni + (size_t)MTOT * 512 * 2);        // 768 KB
  float* Y    = (float*)(uni + (size_t)MTOT * 512 * 2 + 768 * 512 * 2);  // 48 MB
  float* S    = (float*)uni;                                 // 128 MB
  size_t total = off + (size_t)NB * 2048 * 2048 * 4;
  if (ws_size < total) return;  // workspace too small: fail visibly

  hipMemsetAsync(sums, 0, 1536 * sizeof(float), stream);

  cvt_f32_f16<<<8192, 256, 0, stream>>>(X, Xb, (size_t)MTOT * 512 / 4);
  assemble_w<<<384, 256, 0, stream>>>(W1, W2, W3, b1, b2, b3, Wcat, bcat);

  // proj GEMM: Y[16384][768] = leaky(Xb @ Wcat^T + bcat)
  gemm_bt<EPI_BIAS_LEAKY><<<dim3(128, 6, 1), 256, 0, stream>>>(
      Xb, Wcat, Y, CCH, 512, 0, 0, 0, bcat, nullptr);

  bn_stats<<<128, 256, 0, stream>>>(Y, sums);
  bn_finalize<<<3, 256, 0, stream>>>(sums, g1, be1, g2, be2, g3, be3, scale, shift);
  bn_apply_route<<<12288, 256, 0, stream>>>(Y, scale, shift, X1b, X2b, X3b);

  transpose_f16<<<dim3(32, 8, 8), 256, 0, stream>>>(X3b, X3T, 2048, 512);

  // S[b][m][n] = X2[b,m] . X1[b,n]
  gemm_bt<EPI_NONE><<<dim3(16, 16, 8), 256, 0, stream>>>(
      X2b, X1b, S, 2048, 128,
      (size_t)2048 * 128, (size_t)2048 * 128, (size_t)2048 * 2048, nullptr, nullptr);

  row_stats<<<16384, 256, 0, stream>>>(S, Mrow, Zrow);
  softmax_transpose<<<dim3(32, 32, 8), 256, 0, stream>>>(S, Mrow, Zrow, PT);

  // out[b][n][d] = sum_m PT[b][n][m] * X3T[b][d][m] + X[b][n][d]
  gemm_bt<EPI_RESID><<<dim3(16, 4, 8), 256, 0, stream>>>(
      PT, X3T, out, 512, 2048,
      (size_t)2048 * 2048, (size_t)512 * 2048, (size_t)2048 * 512, nullptr, X);
}

// Round 6
// 313.535 us; speedup vs baseline: 1.0066x; 1.0066x over previous
//
#include <hip/hip_runtime.h>

typedef unsigned short u16;
typedef _Float16 f16x8 __attribute__((ext_vector_type(8)));
typedef float f32x4 __attribute__((ext_vector_type(4)));
typedef unsigned int u32x4 __attribute__((ext_vector_type(4)));

#define NB 8
#define NN 2048
#define ND 512
#define NHC 128
#define MTOT (NB*NN)      // 16384
#define CCH 768           // HC + HC + D

__device__ inline u16 f2h(float f) {
  _Float16 h = (_Float16)f;
  return __builtin_bit_cast(u16, h);
}
__device__ inline float h2f(u16 h) {
  return (float)__builtin_bit_cast(_Float16, h);
}

__device__ inline void gld_lds16(const void* g, void* l) {
  __builtin_amdgcn_global_load_lds(
      (__attribute__((address_space(1))) unsigned int*)(g),
      (__attribute__((address_space(3))) unsigned int*)(l), 16, 0, 0);
}

// ---------------- convert / assemble ----------------

__global__ void cvt_f32_f16(const float* __restrict__ in, u16* __restrict__ out, size_t n4) {
  size_t i = (size_t)blockIdx.x * 256 + threadIdx.x;
  if (i >= n4) return;
  float4 v = ((const float4*)in)[i];
  ushort4 o;
  o.x = f2h(v.x); o.y = f2h(v.y); o.z = f2h(v.z); o.w = f2h(v.w);
  ((ushort4*)out)[i] = o;
}

__global__ void assemble_w(const float* __restrict__ W1, const float* __restrict__ W2,
                           const float* __restrict__ W3, const float* __restrict__ b1,
                           const float* __restrict__ b2, const float* __restrict__ b3,
                           u16* __restrict__ Wcat, float* __restrict__ bcat,
                           float* __restrict__ Zrow) {
  int i = blockIdx.x * 256 + threadIdx.x;       // float4 groups: 768*512/4 = 98304
  if (i < 98304) {
    int e = i * 4;
    int rowc = e >> 9;
    int col  = e & 511;
    const float* src = rowc < 128 ? &W1[rowc * 512 + col]
                     : rowc < 256 ? &W2[(rowc - 128) * 512 + col]
                                  : &W3[(rowc - 256) * 512 + col];
    float4 v = *(const float4*)src;
    ushort4 o;
    o.x = f2h(v.x); o.y = f2h(v.y); o.z = f2h(v.z); o.w = f2h(v.w);
    *(ushort4*)&Wcat[e] = o;
  }
  if (i < 768) {
    bcat[i] = i < 128 ? b1[i] : i < 256 ? b2[i - 128] : b3[i - 256];
  }
  if (i < 16384) Zrow[i] = 0.0f;   // zero-init for softmax_transpose atomics
}

// ---------------- GEMM (C[m,n] = sum_k A[m,k]*B[n,k]), m97 structure, fp16 ----------------

enum { EPI_NONE = 0, EPI_BIAS_LEAKY = 1, EPI_RESID = 2, EPI_STATS = 3 };

// TM x TN output tile, 256 threads = 4 waves in 2x2; K-step 64.
template <int EPI, int TM, int TN, bool OUT16>
__global__ __launch_bounds__(256)
void gemm_bt(const u16* __restrict__ A, const u16* __restrict__ B,
             void* __restrict__ Cv, int N, int K,
             size_t sA, size_t sB, size_t sC,
             const float* __restrict__ bias, const float* __restrict__ resid,
             float* __restrict__ Mpart) {
  const int bz = blockIdx.z;
  A += (size_t)bz * sA;
  B += (size_t)bz * sB;
  const int row0 = blockIdx.x * TM, col0 = blockIdx.y * TN;
  __shared__ u16 As[TM * 64];
  __shared__ u16 Bs[TN * 64];
  const int tid  = threadIdx.x;
  const int lane = tid & 63;
  const int wave = tid >> 6;
  constexpr int MF = TM / 32, NF = TN / 32;
  const int wr = (wave >> 1) * (TM / 2), wc = (wave & 1) * (TN / 2);
  const int lr  = lane & 15;
  const int lk8 = (lane >> 4) * 8;
  f32x4 acc[MF][NF] = {};
  for (int kt = 0; kt < K; kt += 64) {
#pragma unroll
    for (int i = 0; i < TM / 32; ++i) {
      int e = i * 256 + tid;
      int r = e >> 3, kc = (e & 7) * 8;
      gld_lds16(A + (size_t)(row0 + r) * K + kt + kc, As + e * 8);
    }
#pragma unroll
    for (int i = 0; i < TN / 32; ++i) {
      int e = i * 256 + tid;
      int r = e >> 3, kc = (e & 7) * 8;
      gld_lds16(B + (size_t)(col0 + r) * K + kt + kc, Bs + e * 8);
    }
    __syncthreads();
#pragma unroll
    for (int kk = 0; kk < 2; ++kk) {
      f16x8 af[MF], bg[NF];
      const int ko = kk * 32 + lk8;
#pragma unroll
      for (int m = 0; m < MF; ++m)
        af[m] = __builtin_bit_cast(f16x8, *(const u32x4*)&As[(wr + m * 16 + lr) * 64 + ko]);
#pragma unroll
      for (int n = 0; n < NF; ++n)
        bg[n] = __builtin_bit_cast(f16x8, *(const u32x4*)&Bs[(wc + n * 16 + lr) * 64 + ko]);
#pragma unroll
      for (int m = 0; m < MF; ++m)
#pragma unroll
        for (int n = 0; n < NF; ++n)
          acc[m][n] = __builtin_amdgcn_mfma_f32_16x16x32_f16(af[m], bg[n], acc[m][n], 0, 0, 0);
    }
    __syncthreads();
  }
  const int lq4 = (lane >> 4) * 4;
#pragma unroll
  for (int m = 0; m < MF; ++m) {
#pragma unroll
    for (int n = 0; n < NF; ++n) {
      const int col = col0 + wc + n * 16 + lr;
#pragma unroll
      for (int r = 0; r < 4; ++r) {
        const int row = row0 + wr + m * 16 + lq4 + r;
        float v = acc[m][n][r];
        if (EPI == EPI_BIAS_LEAKY) { v += bias[col]; v = v >= 0.0f ? v : 0.01f * v; }
        if (EPI == EPI_RESID)      { v += resid[(size_t)bz * sC + (size_t)row * N + col]; }
        if (OUT16) ((u16*)Cv)[(size_t)bz * sC + (size_t)row * N + col] = f2h(v);
        else       ((float*)Cv)[(size_t)bz * sC + (size_t)row * N + col] = v;
      }
    }
  }
  if constexpr (EPI == EPI_STATS) {
    // per-tile row maxima -> Mpart[blockIdx.y][global_row]
    __shared__ float mred[TM][2];
#pragma unroll
    for (int m = 0; m < MF; ++m) {
#pragma unroll
      for (int r = 0; r < 4; ++r) {
        float vx = acc[m][0][r];
#pragma unroll
        for (int n = 1; n < NF; ++n) vx = fmaxf(vx, acc[m][n][r]);
        vx = fmaxf(vx, __shfl_xor(vx, 1));
        vx = fmaxf(vx, __shfl_xor(vx, 2));
        vx = fmaxf(vx, __shfl_xor(vx, 4));
        vx = fmaxf(vx, __shfl_xor(vx, 8));
        if (lr == 0) mred[wr + m * 16 + lq4 + r][wave & 1] = vx;
      }
    }
    __syncthreads();
    if (tid < TM) {
      float v = fmaxf(mred[tid][0], mred[tid][1]);
      Mpart[(size_t)blockIdx.y * MTOT + (size_t)bz * NN + row0 + tid] = v;
    }
  }
}

__global__ void maxreduce(const float* __restrict__ Mpart, float* __restrict__ Mrow) {
  int i = blockIdx.x * 256 + threadIdx.x;   // 16384
  float m = Mpart[i];
#pragma unroll
  for (int j = 1; j < 16; ++j) m = fmaxf(m, Mpart[(size_t)j * MTOT + i]);
  Mrow[i] = m;
}

// ---------------- BatchNorm stats / apply (Y in fp16) ----------------

__global__ void bn_stats(const u16* __restrict__ Yh, float* __restrict__ sums) {
  // grid 128 blocks x 192 threads; thread owns channel quad t; block owns 128 rows
  int t = threadIdx.x;                       // 0..191
  const ushort4* p = (const ushort4*)Yh + (size_t)blockIdx.x * 128 * 192 + t;
  float s0 = 0, s1 = 0, s2 = 0, s3 = 0, q0 = 0, q1 = 0, q2 = 0, q3 = 0;
  for (int r = 0; r < 128; ++r) {
    ushort4 v = p[(size_t)r * 192];
    float a = h2f(v.x), b = h2f(v.y), c = h2f(v.z), d = h2f(v.w);
    s0 += a; s1 += b; s2 += c; s3 += d;
    q0 += a * a; q1 += b * b; q2 += c * c; q3 += d * d;
  }
  int c = t * 4;
  atomicAdd(&sums[c + 0], s0); atomicAdd(&sums[c + 1], s1);
  atomicAdd(&sums[c + 2], s2); atomicAdd(&sums[c + 3], s3);
  atomicAdd(&sums[CCH + c + 0], q0); atomicAdd(&sums[CCH + c + 1], q1);
  atomicAdd(&sums[CCH + c + 2], q2); atomicAdd(&sums[CCH + c + 3], q3);
}

__global__ void bn_finalize(const float* __restrict__ sums,
                            const float* __restrict__ g1, const float* __restrict__ be1,
                            const float* __restrict__ g2, const float* __restrict__ be2,
                            const float* __restrict__ g3, const float* __restrict__ be3,
                            float* __restrict__ scale, float* __restrict__ shift) {
  int c = blockIdx.x * 256 + threadIdx.x;
  if (c >= CCH) return;
  const float inv = 1.0f / (float)MTOT;
  float mu  = sums[c] * inv;
  float var = sums[CCH + c] * inv - mu * mu;
  float g, be;
  if (c < 128)      { g = g1[c];       be = be1[c]; }
  else if (c < 256) { g = g2[c - 128]; be = be2[c - 128]; }
  else              { g = g3[c - 256]; be = be3[c - 256]; }
  float sc = rsqrtf(var + 1e-5f) * g;
  scale[c] = sc;
  shift[c] = be - mu * sc;
}

__global__ void bn_apply_route(const u16* __restrict__ Yh, const float* __restrict__ scale,
                               const float* __restrict__ shift, u16* __restrict__ X1b,
                               u16* __restrict__ X2b, u16* __restrict__ X3b) {
  size_t idx4 = (size_t)blockIdx.x * 256 + threadIdx.x;   // 16384*192 total
  int row = (int)(idx4 / 192);
  int c4  = (int)(idx4 % 192);
  int c   = c4 * 4;
  ushort4 y = ((const ushort4*)Yh)[idx4];
  float4 sc = ((const float4*)scale)[c4];
  float4 sh = ((const float4*)shift)[c4];
  ushort4 o;
  o.x = f2h(h2f(y.x) * sc.x + sh.x);
  o.y = f2h(h2f(y.y) * sc.y + sh.y);
  o.z = f2h(h2f(y.z) * sc.z + sh.z);
  o.w = f2h(h2f(y.w) * sc.w + sh.w);
  if (c < 128)      *(ushort4*)&X1b[(size_t)row * 128 + c] = o;
  else if (c < 256) *(ushort4*)&X2b[(size_t)row * 128 + (c - 128)] = o;
  else              *(ushort4*)&X3b[(size_t)row * 512 + (c - 256)] = o;
}

// ---------------- transposes / softmax ----------------

__global__ void transpose_scale(const u16* __restrict__ in, const float* __restrict__ Zrow,
                                u16* __restrict__ out, int R, int C) {
  // per-batch [R][C] -> [C][R], scaling row m by 1/Zrow[bz*R+m]
  __shared__ u16 tile[64][66];
  int bz = blockIdx.z;
  const u16* ib = in + (size_t)bz * R * C;
  u16* ob = out + (size_t)bz * R * C;
  int r0 = blockIdx.x * 64, c0 = blockIdx.y * 64;
  int t = threadIdx.x, tr = t >> 4, tc4 = (t & 15) * 4;
#pragma unroll
  for (int i = 0; i < 4; ++i) {
    int rl = i * 16 + tr;
    float iz = 1.0f / Zrow[(size_t)bz * R + r0 + rl];
    ushort4 v = *(const ushort4*)&ib[(size_t)(r0 + rl) * C + c0 + tc4];
    tile[tc4 + 0][rl] = f2h(h2f(v.x) * iz);
    tile[tc4 + 1][rl] = f2h(h2f(v.y) * iz);
    tile[tc4 + 2][rl] = f2h(h2f(v.z) * iz);
    tile[tc4 + 3][rl] = f2h(h2f(v.w) * iz);
  }
  __syncthreads();
#pragma unroll
  for (int i = 0; i < 4; ++i) {
    int cl = i * 16 + tr;
    ushort4 o;
    o.x = tile[cl][tc4 + 0]; o.y = tile[cl][tc4 + 1];
    o.z = tile[cl][tc4 + 2]; o.w = tile[cl][tc4 + 3];
    *(ushort4*)&ob[(size_t)(c0 + cl) * R + r0 + tc4] = o;
  }
}

__global__ void softmax_transpose(const float* __restrict__ S, const float* __restrict__ Mrow,
                                  float* __restrict__ Zrow, u16* __restrict__ PT) {
  // e[m][n] = exp(S[m][n]-M[m]); write PTe[n][m] (fp16); accumulate Zrow[m] += row sums
  __shared__ u16 tile[64][66];
  int bz = blockIdx.z;
  const float* Sb = S + (size_t)bz * 2048 * 2048;
  u16* PTb = PT + (size_t)bz * 2048 * 2048;
  int m0 = blockIdx.x * 64, n0 = blockIdx.y * 64;
  int t = threadIdx.x, tm = t >> 4, tn4 = (t & 15) * 4;
#pragma unroll
  for (int i = 0; i < 4; ++i) {
    int ml = i * 16 + tm;
    int m = m0 + ml;
    float4 v = *(const float4*)&Sb[(size_t)m * 2048 + n0 + tn4];
    float mm = Mrow[bz * 2048 + m];
    float e0 = __expf(v.x - mm);
    float e1 = __expf(v.y - mm);
    float e2 = __expf(v.z - mm);
    float e3 = __expf(v.w - mm);
    tile[tn4 + 0][ml] = f2h(e0);
    tile[tn4 + 1][ml] = f2h(e1);
    tile[tn4 + 2][ml] = f2h(e2);
    tile[tn4 + 3][ml] = f2h(e3);
    float ss = (e0 + e1) + (e2 + e3);
    ss += __shfl_xor(ss, 1);
    ss += __shfl_xor(ss, 2);
    ss += __shfl_xor(ss, 4);
    ss += __shfl_xor(ss, 8);
    if ((t & 15) == 0) atomicAdd(&Zrow[bz * 2048 + m], ss);
  }
  __syncthreads();
#pragma unroll
  for (int i = 0; i < 4; ++i) {
    int nl = i * 16 + tm;
    ushort4 o;
    o.x = tile[nl][tn4 + 0]; o.y = tile[nl][tn4 + 1];
    o.z = tile[nl][tn4 + 2]; o.w = tile[nl][tn4 + 3];
    *(ushort4*)&PTb[(size_t)(n0 + nl) * 2048 + m0 + tn4] = o;
  }
}

// ---------------- launch ----------------

extern "C" void kernel_launch(void* const* d_in, const int* in_sizes, int n_in,
                              void* d_out, int out_size, void* d_ws, size_t ws_size,
                              hipStream_t stream) {
  const float* X   = (const float*)d_in[0];
  const float* W1  = (const float*)d_in[1];
  const float* b1  = (const float*)d_in[2];
  const float* g1  = (const float*)d_in[3];
  const float* be1 = (const float*)d_in[4];
  const float* W2  = (const float*)d_in[5];
  const float* b2  = (const float*)d_in[6];
  const float* g2  = (const float*)d_in[7];
  const float* be2 = (const float*)d_in[8];
  const float* W3  = (const float*)d_in[9];
  const float* b3  = (const float*)d_in[10];
  const float* g3  = (const float*)d_in[11];
  const float* be3 = (const float*)d_in[12];
  float* out = (float*)d_out;

  char* ws = (char*)d_ws;
  // small region
  float* sums  = (float*)ws;                 // 1536
  float* scale = sums + 1536;                // 768
  float* shift = scale + 768;                // 768
  float* bcat  = shift + 768;                // 768
  float* Mrow  = bcat + 768;                 // 16384
  float* Zrow  = Mrow + 16384;               // 16384
  float* Mpart = Zrow + 16384;               // 16*16384
  size_t off = (size_t)(1536 + 768 + 768 + 768 + 16384 + 16384 + 16 * 16384) * 4;
  // persistent fp16 region
  u16* X1b = (u16*)(ws + off); off += (size_t)MTOT * 128 * 2;
  u16* X2b = (u16*)(ws + off); off += (size_t)MTOT * 128 * 2;
  u16* X3b = (u16*)(ws + off); off += (size_t)MTOT * 512 * 2;
  u16* X3T = (u16*)(ws + off); off += (size_t)MTOT * 512 * 2;
  u16* PT  = (u16*)(ws + off); off += (size_t)NB * 2048 * 2048 * 2;
  // union region: {Xb, Wcat, Yh} (dead before S is written) overlaid with S
  char* uni = ws + off;
  u16*   Xb   = (u16*)uni;                                       // 16 MB
  u16*   Wcat = (u16*)(uni + (size_t)MTOT * 512 * 2);            // 768 KB
  u16*   Yh   = (u16*)(uni + (size_t)MTOT * 512 * 2 + 768 * 512 * 2);  // 24 MB fp16
  float* S    = (float*)uni;                                     // 128 MB
  size_t total = off + (size_t)NB * 2048 * 2048 * 4;
  if (ws_size < total) return;  // workspace too small: fail visibly

  hipMemsetAsync(sums, 0, 1536 * sizeof(float), stream);

  cvt_f32_f16<<<8192, 256, 0, stream>>>(X, Xb, (size_t)MTOT * 512 / 4);
  assemble_w<<<384, 256, 0, stream>>>(W1, W2, W3, b1, b2, b3, Wcat, bcat, Zrow);

  // proj GEMM: Yh[16384][768] = fp16(leaky(Xb @ Wcat^T + bcat))
  gemm_bt<EPI_BIAS_LEAKY, 128, 128, true><<<dim3(128, 6, 1), 256, 0, stream>>>(
      Xb, Wcat, Yh, CCH, 512, 0, 0, 0, bcat, nullptr, nullptr);

  bn_stats<<<128, 192, 0, stream>>>(Yh, sums);
  bn_finalize<<<3, 256, 0, stream>>>(sums, g1, be1, g2, be2, g3, be3, scale, shift);
  bn_apply_route<<<12288, 256, 0, stream>>>(Yh, scale, shift, X1b, X2b, X3b);

  // S[b][m][n] = X2[b,m] . X1[b,n]  (f32) + per-tile row-max partials
  gemm_bt<EPI_STATS, 128, 128, false><<<dim3(16, 16, 8), 256, 0, stream>>>(
      X2b, X1b, S, 2048, 128,
      (size_t)2048 * 128, (size_t)2048 * 128, (size_t)2048 * 2048, nullptr, nullptr, Mpart);

  maxreduce<<<64, 256, 0, stream>>>(Mpart, Mrow);

  // PTe[n][m] = fp16(exp(S[m][n]-M[m])); Zrow[m] += row sums
  softmax_transpose<<<dim3(32, 32, 8), 256, 0, stream>>>(S, Mrow, Zrow, PT);

  // X3T[d][m] = fp16(X3[m][d] / Z[m])
  transpose_scale<<<dim3(32, 8, 8), 256, 0, stream>>>(X3b, Zrow, X3T, 2048, 512);

  // out[b][n][d] = sum_m PTe[b][n][m] * X3T[b][d][m] + X[b][n][d]
  gemm_bt<EPI_RESID, 64, 128, false><<<dim3(32, 4, 8), 256, 0, stream>>>(
      PT, X3T, out, 512, 2048,
      (size_t)2048 * 2048, (size_t)512 * 2048, (size_t)2048 * 512, nullptr, X, nullptr);
}

// Round 7
// 310.724 us; speedup vs baseline: 1.0157x; 1.0090x over previous
//
#include <hip/hip_runtime.h>

typedef unsigned short u16;
typedef _Float16 f16x8 __attribute__((ext_vector_type(8)));
typedef float f32x4 __attribute__((ext_vector_type(4)));
typedef unsigned int u32x4 __attribute__((ext_vector_type(4)));

#define NB 8
#define NN 2048
#define ND 512
#define NHC 128
#define MTOT (NB*NN)      // 16384
#define CCH 768           // HC + HC + D

__device__ inline u16 f2h(float f) {
  _Float16 h = (_Float16)f;
  return __builtin_bit_cast(u16, h);
}
__device__ inline float h2f(u16 h) {
  return (float)__builtin_bit_cast(_Float16, h);
}

__device__ inline void gld_lds16(const void* g, void* l) {
  __builtin_amdgcn_global_load_lds(
      (__attribute__((address_space(1))) unsigned int*)(g),
      (__attribute__((address_space(3))) unsigned int*)(l), 16, 0, 0);
}

// ---------------- convert / assemble ----------------

__global__ void cvt_f32_f16(const float* __restrict__ in, u16* __restrict__ out, size_t n4) {
  size_t i = (size_t)blockIdx.x * 256 + threadIdx.x;
  if (i >= n4) return;
  float4 v = ((const float4*)in)[i];
  ushort4 o;
  o.x = f2h(v.x); o.y = f2h(v.y); o.z = f2h(v.z); o.w = f2h(v.w);
  ((ushort4*)out)[i] = o;
}

__global__ void assemble_w(const float* __restrict__ W1, const float* __restrict__ W2,
                           const float* __restrict__ W3, const float* __restrict__ b1,
                           const float* __restrict__ b2, const float* __restrict__ b3,
                           u16* __restrict__ Wcat, float* __restrict__ bcat) {
  int i = blockIdx.x * 256 + threadIdx.x;       // float4 groups: 768*512/4 = 98304
  if (i < 98304) {
    int e = i * 4;
    int rowc = e >> 9;
    int col  = e & 511;
    const float* src = rowc < 128 ? &W1[rowc * 512 + col]
                     : rowc < 256 ? &W2[(rowc - 128) * 512 + col]
                                  : &W3[(rowc - 256) * 512 + col];
    float4 v = *(const float4*)src;
    ushort4 o;
    o.x = f2h(v.x); o.y = f2h(v.y); o.z = f2h(v.z); o.w = f2h(v.w);
    *(ushort4*)&Wcat[e] = o;
  }
  if (i < 768) {
    bcat[i] = i < 128 ? b1[i] : i < 256 ? b2[i - 128] : b3[i - 256];
  }
}

// ---------------- GEMM (C[m,n] = sum_k A[m,k]*B[n,k]), m97 structure, fp16 ----------------

enum { EPI_NONE = 0, EPI_BIAS_LEAKY = 1, EPI_STATS = 3 };

// TM x TN output tile, 256 threads = 4 waves in 2x2; K-step 64.
template <int EPI, int TM, int TN, bool OUT16>
__global__ __launch_bounds__(256)
void gemm_bt(const u16* __restrict__ A, const u16* __restrict__ B,
             void* __restrict__ Cv, int N, int K,
             size_t sA, size_t sB, size_t sC,
             const float* __restrict__ bias, float* __restrict__ Mpart) {
  const int bz = blockIdx.z;
  A += (size_t)bz * sA;
  B += (size_t)bz * sB;
  const int row0 = blockIdx.x * TM, col0 = blockIdx.y * TN;
  __shared__ __attribute__((aligned(16))) u16 As[TM * 64];
  __shared__ __attribute__((aligned(16))) u16 Bs[TN * 64];
  const int tid  = threadIdx.x;
  const int lane = tid & 63;
  const int wave = tid >> 6;
  constexpr int MF = TM / 32, NF = TN / 32;
  const int wr = (wave >> 1) * (TM / 2), wc = (wave & 1) * (TN / 2);
  const int lr  = lane & 15;
  const int lk8 = (lane >> 4) * 8;
  f32x4 acc[MF][NF] = {};
  for (int kt = 0; kt < K; kt += 64) {
#pragma unroll
    for (int i = 0; i < TM / 32; ++i) {
      int e = i * 256 + tid;
      int r = e >> 3, kc = (e & 7) * 8;
      gld_lds16(A + (size_t)(row0 + r) * K + kt + kc, As + e * 8);
    }
#pragma unroll
    for (int i = 0; i < TN / 32; ++i) {
      int e = i * 256 + tid;
      int r = e >> 3, kc = (e & 7) * 8;
      gld_lds16(B + (size_t)(col0 + r) * K + kt + kc, Bs + e * 8);
    }
    __syncthreads();
#pragma unroll
    for (int kk = 0; kk < 2; ++kk) {
      f16x8 af[MF], bg[NF];
      const int ko = kk * 32 + lk8;
#pragma unroll
      for (int m = 0; m < MF; ++m)
        af[m] = __builtin_bit_cast(f16x8, *(const u32x4*)&As[(wr + m * 16 + lr) * 64 + ko]);
#pragma unroll
      for (int n = 0; n < NF; ++n)
        bg[n] = __builtin_bit_cast(f16x8, *(const u32x4*)&Bs[(wc + n * 16 + lr) * 64 + ko]);
#pragma unroll
      for (int m = 0; m < MF; ++m)
#pragma unroll
        for (int n = 0; n < NF; ++n)
          acc[m][n] = __builtin_amdgcn_mfma_f32_16x16x32_f16(af[m], bg[n], acc[m][n], 0, 0, 0);
    }
    __syncthreads();
  }
  const int lq4 = (lane >> 4) * 4;
#pragma unroll
  for (int m = 0; m < MF; ++m) {
#pragma unroll
    for (int n = 0; n < NF; ++n) {
      const int col = col0 + wc + n * 16 + lr;
#pragma unroll
      for (int r = 0; r < 4; ++r) {
        const int row = row0 + wr + m * 16 + lq4 + r;
        float v = acc[m][n][r];
        if (EPI == EPI_BIAS_LEAKY) { v += bias[col]; v = v >= 0.0f ? v : 0.01f * v; }
        if (OUT16) ((u16*)Cv)[(size_t)bz * sC + (size_t)row * N + col] = f2h(v);
        else       ((float*)Cv)[(size_t)bz * sC + (size_t)row * N + col] = v;
      }
    }
  }
  if constexpr (EPI == EPI_STATS) {
    // per-tile row maxima -> Mpart[blockIdx.y][global_row]
    __shared__ float mred[TM][2];
#pragma unroll
    for (int m = 0; m < MF; ++m) {
#pragma unroll
      for (int r = 0; r < 4; ++r) {
        float vx = acc[m][0][r];
#pragma unroll
        for (int n = 1; n < NF; ++n) vx = fmaxf(vx, acc[m][n][r]);
        vx = fmaxf(vx, __shfl_xor(vx, 1));
        vx = fmaxf(vx, __shfl_xor(vx, 2));
        vx = fmaxf(vx, __shfl_xor(vx, 4));
        vx = fmaxf(vx, __shfl_xor(vx, 8));
        if (lr == 0) mred[wr + m * 16 + lq4 + r][wave & 1] = vx;
      }
    }
    __syncthreads();
    if (tid < TM) {
      float v = fmaxf(mred[tid][0], mred[tid][1]);
      Mpart[(size_t)blockIdx.y * MTOT + (size_t)bz * NN + row0 + tid] = v;
    }
  }
}

__global__ void maxreduce(const float* __restrict__ Mpart, float* __restrict__ Mrow) {
  int i = blockIdx.x * 256 + threadIdx.x;   // 16384
  float m = Mpart[i];
#pragma unroll
  for (int j = 1; j < 16; ++j) m = fmaxf(m, Mpart[(size_t)j * MTOT + i]);
  Mrow[i] = m;
}

// Z[row] = sum_n exp(S16[row][n] - M[row]); one block per row
__global__ void zpass(const u16* __restrict__ S, const float* __restrict__ Mrow,
                      float* __restrict__ Zrow) {
  int row = blockIdx.x;
  const ushort4* r = (const ushort4*)(S + (size_t)row * NN);
  float mm = Mrow[row];
  int t = threadIdx.x;
  ushort4 a = r[t * 2], b = r[t * 2 + 1];
  float s = __expf(h2f(a.x) - mm) + __expf(h2f(a.y) - mm)
          + __expf(h2f(a.z) - mm) + __expf(h2f(a.w) - mm)
          + __expf(h2f(b.x) - mm) + __expf(h2f(b.y) - mm)
          + __expf(h2f(b.z) - mm) + __expf(h2f(b.w) - mm);
#pragma unroll
  for (int off = 32; off; off >>= 1) s += __shfl_xor(s, off);
  __shared__ float zz[4];
  int wave = t >> 6, lane = t & 63;
  if (lane == 0) zz[wave] = s;
  __syncthreads();
  if (t == 0) Zrow[row] = zz[0] + zz[1] + zz[2] + zz[3];
}

// ---------------- fused PV GEMM: out[n][d] = sum_m exp(S[m][n]-M[m]) * X3T'[d][m] + Xb[n][d]
__global__ __launch_bounds__(256)
void gemm_pv(const u16* __restrict__ S, const float* __restrict__ Mrow,
             const u16* __restrict__ X3T, const u16* __restrict__ Xb,
             float* __restrict__ out) {
  const int bz = blockIdx.z;
  const u16* Sb = S + (size_t)bz * NN * NN;
  const u16* Bb = X3T + (size_t)bz * (size_t)ND * NN;
  const int row0 = blockIdx.x * 64;        // n tile
  const int col0 = blockIdx.y * 128;       // d tile
  __shared__ __attribute__((aligned(16))) u16 As2[64 * 72];  // [n][72 m-padded]
  __shared__ __attribute__((aligned(16))) u16 Bs[128 * 64];
  const int tid = threadIdx.x, lane = tid & 63, wave = tid >> 6;
  const int wr = (wave >> 1) * 32, wc = (wave & 1) * 64;
  const int lr = lane & 15, lk8 = (lane >> 4) * 8;
  const int sm_ = tid >> 2;                // m-local 0..63 (fixed per thread)
  const int snq = tid & 3;
  f32x4 acc[2][4] = {};
  for (int kt = 0; kt < NN; kt += 64) {
    // stage B (X3T' rows d, k=m) async
#pragma unroll
    for (int i = 0; i < 4; ++i) {
      int e = i * 256 + tid;
      int r = e >> 3, kc = (e & 7) * 8;
      gld_lds16(Bb + (size_t)(col0 + r) * NN + kt + kc, Bs + e * 8);
    }
    // stage A = E^T via regs: read S[m][n] coalesced, exp, transpose into LDS
    float Mv = Mrow[bz * NN + kt + sm_];
#pragma unroll
    for (int i = 0; i < 4; ++i) {
      int nq = snq + i * 4;
      ushort4 v = *(const ushort4*)&Sb[(size_t)(kt + sm_) * NN + row0 + nq * 4];
      As2[(nq * 4 + 0) * 72 + sm_] = f2h(__expf(h2f(v.x) - Mv));
      As2[(nq * 4 + 1) * 72 + sm_] = f2h(__expf(h2f(v.y) - Mv));
      As2[(nq * 4 + 2) * 72 + sm_] = f2h(__expf(h2f(v.z) - Mv));
      As2[(nq * 4 + 3) * 72 + sm_] = f2h(__expf(h2f(v.w) - Mv));
    }
    __syncthreads();
#pragma unroll
    for (int kk = 0; kk < 2; ++kk) {
      f16x8 af[2], bg[4];
      const int ko = kk * 32 + lk8;
#pragma unroll
      for (int m = 0; m < 2; ++m)
        af[m] = __builtin_bit_cast(f16x8, *(const u32x4*)&As2[(wr + m * 16 + lr) * 72 + ko]);
#pragma unroll
      for (int n = 0; n < 4; ++n)
        bg[n] = __builtin_bit_cast(f16x8, *(const u32x4*)&Bs[(wc + n * 16 + lr) * 64 + ko]);
#pragma unroll
      for (int m = 0; m < 2; ++m)
#pragma unroll
        for (int n = 0; n < 4; ++n)
          acc[m][n] = __builtin_amdgcn_mfma_f32_16x16x32_f16(af[m], bg[n], acc[m][n], 0, 0, 0);
    }
    __syncthreads();
  }
  const int lq4 = (lane >> 4) * 4;
#pragma unroll
  for (int m = 0; m < 2; ++m) {
#pragma unroll
    for (int n = 0; n < 4; ++n) {
      const int col = col0 + wc + n * 16 + lr;
#pragma unroll
      for (int r = 0; r < 4; ++r) {
        const int row = row0 + wr + m * 16 + lq4 + r;
        float v = acc[m][n][r] + h2f(Xb[((size_t)bz * NN + row) * ND + col]);
        out[((size_t)bz * NN + row) * (size_t)ND + col] = v;
      }
    }
  }
}

// ---------------- BatchNorm stats / apply (Y in fp16) ----------------

__global__ void bn_stats(const u16* __restrict__ Yh, float* __restrict__ sums) {
  int t = threadIdx.x;                       // 0..191
  const ushort4* p = (const ushort4*)Yh + (size_t)blockIdx.x * 128 * 192 + t;
  float s0 = 0, s1 = 0, s2 = 0, s3 = 0, q0 = 0, q1 = 0, q2 = 0, q3 = 0;
  for (int r = 0; r < 128; ++r) {
    ushort4 v = p[(size_t)r * 192];
    float a = h2f(v.x), b = h2f(v.y), c = h2f(v.z), d = h2f(v.w);
    s0 += a; s1 += b; s2 += c; s3 += d;
    q0 += a * a; q1 += b * b; q2 += c * c; q3 += d * d;
  }
  int c = t * 4;
  atomicAdd(&sums[c + 0], s0); atomicAdd(&sums[c + 1], s1);
  atomicAdd(&sums[c + 2], s2); atomicAdd(&sums[c + 3], s3);
  atomicAdd(&sums[CCH + c + 0], q0); atomicAdd(&sums[CCH + c + 1], q1);
  atomicAdd(&sums[CCH + c + 2], q2); atomicAdd(&sums[CCH + c + 3], q3);
}

__global__ void bn_finalize(const float* __restrict__ sums,
                            const float* __restrict__ g1, const float* __restrict__ be1,
                            const float* __restrict__ g2, const float* __restrict__ be2,
                            const float* __restrict__ g3, const float* __restrict__ be3,
                            float* __restrict__ scale, float* __restrict__ shift) {
  int c = blockIdx.x * 256 + threadIdx.x;
  if (c >= CCH) return;
  const float inv = 1.0f / (float)MTOT;
  float mu  = sums[c] * inv;
  float var = sums[CCH + c] * inv - mu * mu;
  float g, be;
  if (c < 128)      { g = g1[c];       be = be1[c]; }
  else if (c < 256) { g = g2[c - 128]; be = be2[c - 128]; }
  else              { g = g3[c - 256]; be = be3[c - 256]; }
  float sc = rsqrtf(var + 1e-5f) * g;
  scale[c] = sc;
  shift[c] = be - mu * sc;
}

__global__ void bn_apply_route(const u16* __restrict__ Yh, const float* __restrict__ scale,
                               const float* __restrict__ shift, u16* __restrict__ X1b,
                               u16* __restrict__ X2b, u16* __restrict__ X3b) {
  size_t idx4 = (size_t)blockIdx.x * 256 + threadIdx.x;   // 16384*192 total
  int row = (int)(idx4 / 192);
  int c4  = (int)(idx4 % 192);
  int c   = c4 * 4;
  ushort4 y = ((const ushort4*)Yh)[idx4];
  float4 sc = ((const float4*)scale)[c4];
  float4 sh = ((const float4*)shift)[c4];
  ushort4 o;
  o.x = f2h(h2f(y.x) * sc.x + sh.x);
  o.y = f2h(h2f(y.y) * sc.y + sh.y);
  o.z = f2h(h2f(y.z) * sc.z + sh.z);
  o.w = f2h(h2f(y.w) * sc.w + sh.w);
  if (c < 128)      *(ushort4*)&X1b[(size_t)row * 128 + c] = o;
  else if (c < 256) *(ushort4*)&X2b[(size_t)row * 128 + (c - 128)] = o;
  else              *(ushort4*)&X3b[(size_t)row * 512 + (c - 256)] = o;
}

// ---------------- X3 transpose with 1/Z fold ----------------

__global__ void transpose_scale(const u16* __restrict__ in, const float* __restrict__ Zrow,
                                u16* __restrict__ out, int R, int C) {
  // per-batch [R][C] -> [C][R], scaling row m by 1/Zrow[bz*R+m]
  __shared__ u16 tile[64][66];
  int bz = blockIdx.z;
  const u16* ib = in + (size_t)bz * R * C;
  u16* ob = out + (size_t)bz * R * C;
  int r0 = blockIdx.x * 64, c0 = blockIdx.y * 64;
  int t = threadIdx.x, tr = t >> 4, tc4 = (t & 15) * 4;
#pragma unroll
  for (int i = 0; i < 4; ++i) {
    int rl = i * 16 + tr;
    float iz = 1.0f / Zrow[(size_t)bz * R + r0 + rl];
    ushort4 v = *(const ushort4*)&ib[(size_t)(r0 + rl) * C + c0 + tc4];
    tile[tc4 + 0][rl] = f2h(h2f(v.x) * iz);
    tile[tc4 + 1][rl] = f2h(h2f(v.y) * iz);
    tile[tc4 + 2][rl] = f2h(h2f(v.z) * iz);
    tile[tc4 + 3][rl] = f2h(h2f(v.w) * iz);
  }
  __syncthreads();
#pragma unroll
  for (int i = 0; i < 4; ++i) {
    int cl = i * 16 + tr;
    ushort4 o;
    o.x = tile[cl][tc4 + 0]; o.y = tile[cl][tc4 + 1];
    o.z = tile[cl][tc4 + 2]; o.w = tile[cl][tc4 + 3];
    *(ushort4*)&ob[(size_t)(c0 + cl) * R + r0 + tc4] = o;
  }
}

// ---------------- launch ----------------

extern "C" void kernel_launch(void* const* d_in, const int* in_sizes, int n_in,
                              void* d_out, int out_size, void* d_ws, size_t ws_size,
                              hipStream_t stream) {
  const float* X   = (const float*)d_in[0];
  const float* W1  = (const float*)d_in[1];
  const float* b1  = (const float*)d_in[2];
  const float* g1  = (const float*)d_in[3];
  const float* be1 = (const float*)d_in[4];
  const float* W2  = (const float*)d_in[5];
  const float* b2  = (const float*)d_in[6];
  const float* g2  = (const float*)d_in[7];
  const float* be2 = (const float*)d_in[8];
  const float* W3  = (const float*)d_in[9];
  const float* b3  = (const float*)d_in[10];
  const float* g3  = (const float*)d_in[11];
  const float* be3 = (const float*)d_in[12];
  float* out = (float*)d_out;

  char* ws = (char*)d_ws;
  // small region
  float* sums  = (float*)ws;                 // 1536
  float* scale = sums + 1536;                // 768
  float* shift = scale + 768;                // 768
  float* bcat  = shift + 768;                // 768
  float* Mrow  = bcat + 768;                 // 16384
  float* Zrow  = Mrow + 16384;               // 16384
  float* Mpart = Zrow + 16384;               // 16*16384
  size_t off = (size_t)(1536 + 768 + 768 + 768 + 16384 + 16384 + 16 * 16384) * 4;
  // persistent fp16 region
  u16* X1b = (u16*)(ws + off); off += (size_t)MTOT * 128 * 2;
  u16* X2b = (u16*)(ws + off); off += (size_t)MTOT * 128 * 2;
  u16* X3b = (u16*)(ws + off); off += (size_t)MTOT * 512 * 2;
  u16* X3T = (u16*)(ws + off); off += (size_t)MTOT * 512 * 2;
  u16* Xb  = (u16*)(ws + off); off += (size_t)MTOT * 512 * 2;
  // union region: {Wcat, Yh} (dead before S is written) overlaid with fp16 S
  char* uni = ws + off;
  u16* Wcat = (u16*)uni;                               // 768 KB
  u16* Yh   = (u16*)(uni + 768 * 512 * 2);             // 24 MB fp16
  u16* S    = (u16*)uni;                               // 64 MB fp16
  size_t total = off + (size_t)NB * NN * NN * 2;
  if (ws_size < total) return;  // workspace too small: fail visibly

  hipMemsetAsync(sums, 0, 1536 * sizeof(float), stream);

  cvt_f32_f16<<<8192, 256, 0, stream>>>(X, Xb, (size_t)MTOT * 512 / 4);
  assemble_w<<<384, 256, 0, stream>>>(W1, W2, W3, b1, b2, b3, Wcat, bcat);

  // proj GEMM: Yh[16384][768] = fp16(leaky(Xb @ Wcat^T + bcat))
  gemm_bt<EPI_BIAS_LEAKY, 128, 128, true><<<dim3(128, 6, 1), 256, 0, stream>>>(
      Xb, Wcat, Yh, CCH, 512, 0, 0, 0, bcat, nullptr);

  bn_stats<<<128, 192, 0, stream>>>(Yh, sums);
  bn_finalize<<<3, 256, 0, stream>>>(sums, g1, be1, g2, be2, g3, be3, scale, shift);
  bn_apply_route<<<12288, 256, 0, stream>>>(Yh, scale, shift, X1b, X2b, X3b);

  // S[b][m][n] = fp16(X2[b,m] . X1[b,n]) + per-tile row-max partials
  gemm_bt<EPI_STATS, 128, 128, true><<<dim3(16, 16, 8), 256, 0, stream>>>(
      X2b, X1b, S, 2048, 128,
      (size_t)2048 * 128, (size_t)2048 * 128, (size_t)2048 * 2048, nullptr, Mpart);

  maxreduce<<<64, 256, 0, stream>>>(Mpart, Mrow);
  zpass<<<16384, 256, 0, stream>>>(S, Mrow, Zrow);

  // X3T[d][m] = fp16(X3[m][d] / Z[m])
  transpose_scale<<<dim3(32, 8, 8), 256, 0, stream>>>(X3b, Zrow, X3T, 2048, 512);

  // out[b][n][d] = sum_m exp(S[m][n]-M[m]) * X3T[d][m] + Xb[n][d]
  gemm_pv<<<dim3(32, 4, 8), 256, 0, stream>>>(S, Mrow, X3T, Xb, out);
}

// Round 9
// 285.600 us; speedup vs baseline: 1.1050x; 1.0880x over previous
//
#include <hip/hip_runtime.h>

typedef unsigned short u16;
typedef _Float16 f16x8 __attribute__((ext_vector_type(8)));
typedef float f32x4 __attribute__((ext_vector_type(4)));
typedef unsigned int u32x4 __attribute__((ext_vector_type(4)));

#define NB 8
#define NN 2048
#define ND 512
#define NHC 128
#define MTOT (NB*NN)      // 16384
#define CCH 768           // HC + HC + D

__device__ inline u16 f2h(float f) {
  _Float16 h = (_Float16)f;
  return __builtin_bit_cast(u16, h);
}
__device__ inline float h2f(u16 h) {
  return (float)__builtin_bit_cast(_Float16, h);
}

__device__ inline void gld_lds16(const void* g, void* l) {
  __builtin_amdgcn_global_load_lds(
      (__attribute__((address_space(1))) unsigned int*)(g),
      (__attribute__((address_space(3))) unsigned int*)(l), 16, 0, 0);
}

union U8 { u32x4 v; u16 h[8]; };

// ---------------- convert / assemble ----------------

__global__ void cvt_f32_f16(const float* __restrict__ in, u16* __restrict__ out, size_t n4) {
  size_t i = (size_t)blockIdx.x * 256 + threadIdx.x;
  if (i >= n4) return;
  float4 v = ((const float4*)in)[i];
  ushort4 o;
  o.x = f2h(v.x); o.y = f2h(v.y); o.z = f2h(v.z); o.w = f2h(v.w);
  ((ushort4*)out)[i] = o;
}

__global__ void assemble_w(const float* __restrict__ W1, const float* __restrict__ W2,
                           const float* __restrict__ W3, const float* __restrict__ b1,
                           const float* __restrict__ b2, const float* __restrict__ b3,
                           u16* __restrict__ Wcat, float* __restrict__ bcat) {
  int i = blockIdx.x * 256 + threadIdx.x;       // float4 groups: 768*512/4 = 98304
  if (i < 98304) {
    int e = i * 4;
    int rowc = e >> 9;
    int col  = e & 511;
    const float* src = rowc < 128 ? &W1[rowc * 512 + col]
                     : rowc < 256 ? &W2[(rowc - 128) * 512 + col]
                                  : &W3[(rowc - 256) * 512 + col];
    float4 v = *(const float4*)src;
    ushort4 o;
    o.x = f2h(v.x); o.y = f2h(v.y); o.z = f2h(v.z); o.w = f2h(v.w);
    *(ushort4*)&Wcat[e] = o;
  }
  if (i < 768) {
    bcat[i] = i < 128 ? b1[i] : i < 256 ? b2[i - 128] : b3[i - 256];
  }
}

// ---------------- proj GEMM (C[m,n] = sum_k A[m,k]*B[n,k]), m97 structure, fp16 ----------------

enum { EPI_NONE = 0, EPI_BIAS_LEAKY = 1 };

template <int EPI, int TM, int TN, bool OUT16>
__global__ __launch_bounds__(256)
void gemm_bt(const u16* __restrict__ A, const u16* __restrict__ B,
             void* __restrict__ Cv, int N, int K,
             size_t sA, size_t sB, size_t sC,
             const float* __restrict__ bias) {
  const int bz = blockIdx.z;
  A += (size_t)bz * sA;
  B += (size_t)bz * sB;
  const int row0 = blockIdx.x * TM, col0 = blockIdx.y * TN;
  __shared__ __attribute__((aligned(16))) u16 As[TM * 64];
  __shared__ __attribute__((aligned(16))) u16 Bs[TN * 64];
  const int tid  = threadIdx.x;
  const int lane = tid & 63;
  const int wave = tid >> 6;
  constexpr int MF = TM / 32, NF = TN / 32;
  const int wr = (wave >> 1) * (TM / 2), wc = (wave & 1) * (TN / 2);
  const int lr  = lane & 15;
  const int lk8 = (lane >> 4) * 8;
  f32x4 acc[MF][NF] = {};
  for (int kt = 0; kt < K; kt += 64) {
#pragma unroll
    for (int i = 0; i < TM / 32; ++i) {
      int e = i * 256 + tid;
      int r = e >> 3, kc = (e & 7) * 8;
      gld_lds16(A + (size_t)(row0 + r) * K + kt + kc, As + e * 8);
    }
#pragma unroll
    for (int i = 0; i < TN / 32; ++i) {
      int e = i * 256 + tid;
      int r = e >> 3, kc = (e & 7) * 8;
      gld_lds16(B + (size_t)(col0 + r) * K + kt + kc, Bs + e * 8);
    }
    __syncthreads();
#pragma unroll
    for (int kk = 0; kk < 2; ++kk) {
      f16x8 af[MF], bg[NF];
      const int ko = kk * 32 + lk8;
#pragma unroll
      for (int m = 0; m < MF; ++m)
        af[m] = __builtin_bit_cast(f16x8, *(const u32x4*)&As[(wr + m * 16 + lr) * 64 + ko]);
#pragma unroll
      for (int n = 0; n < NF; ++n)
        bg[n] = __builtin_bit_cast(f16x8, *(const u32x4*)&Bs[(wc + n * 16 + lr) * 64 + ko]);
#pragma unroll
      for (int m = 0; m < MF; ++m)
#pragma unroll
        for (int n = 0; n < NF; ++n)
          acc[m][n] = __builtin_amdgcn_mfma_f32_16x16x32_f16(af[m], bg[n], acc[m][n], 0, 0, 0);
    }
    __syncthreads();
  }
  const int lq4 = (lane >> 4) * 4;
#pragma unroll
  for (int m = 0; m < MF; ++m) {
#pragma unroll
    for (int n = 0; n < NF; ++n) {
      const int col = col0 + wc + n * 16 + lr;
#pragma unroll
      for (int r = 0; r < 4; ++r) {
        const int row = row0 + wr + m * 16 + lq4 + r;
        float v = acc[m][n][r];
        if (EPI == EPI_BIAS_LEAKY) { v += bias[col]; v = v >= 0.0f ? v : 0.01f * v; }
        if (OUT16) ((u16*)Cv)[(size_t)bz * sC + (size_t)row * N + col] = f2h(v);
        else       ((float*)Cv)[(size_t)bz * sC + (size_t)row * N + col] = v;
      }
    }
  }
}

// ---------------- one-shot S GEMM: ST[n][m] = X1[n].X2[m], K=128, 256x256 tile ----------------
// epilogue: fp16 store + per-(16-rowchunk) column max and column Z partials.

__global__ __launch_bounds__(512)
void gemm_s(const u16* __restrict__ X1, const u16* __restrict__ X2,
            u16* __restrict__ ST, float* __restrict__ Mpart, float* __restrict__ Zpart) {
  const int bz = blockIdx.z;
  X1 += (size_t)bz * NN * NHC;
  X2 += (size_t)bz * NN * NHC;
  u16* STb = ST + (size_t)bz * NN * NN;
  const int row0 = blockIdx.x * 256;   // n
  const int col0 = blockIdx.y * 256;   // m
  __shared__ __attribute__((aligned(16))) u16 As[256 * 128];
  __shared__ __attribute__((aligned(16))) u16 Bs[256 * 128];
  const int tid = threadIdx.x, lane = tid & 63, wave = tid >> 6;
  const int lr = lane & 15, lk8 = (lane >> 4) * 8;
  const int wr = (wave >> 2) * 128, wc = (wave & 3) * 64;
  // stage; source pre-swizzled so linear LDS + XOR read is bank-friendly (rule #21)
#pragma unroll
  for (int i = 0; i < 8; ++i) {
    int e = i * 512 + tid;
    int r = e >> 4;
    int kc = ((e & 15) ^ (r & 7)) * 8;
    gld_lds16(X1 + (size_t)(row0 + r) * NHC + kc, As + e * 8);
  }
#pragma unroll
  for (int i = 0; i < 8; ++i) {
    int e = i * 512 + tid;
    int r = e >> 4;
    int kc = ((e & 15) ^ (r & 7)) * 8;
    gld_lds16(X2 + (size_t)(col0 + r) * NHC + kc, Bs + e * 8);
  }
  __syncthreads();
  f32x4 acc[8][4] = {};
#pragma unroll
  for (int kk = 0; kk < 4; ++kk) {
    const int ko = kk * 32 + lk8;
    f16x8 af[8], bg[4];
#pragma unroll
    for (int m = 0; m < 8; ++m) {
      int rr = wr + m * 16 + lr;
      af[m] = __builtin_bit_cast(f16x8, *(const u32x4*)&As[rr * 128 + (ko ^ ((rr & 7) * 8))]);
    }
#pragma unroll
    for (int n = 0; n < 4; ++n) {
      int rr = wc + n * 16 + lr;
      bg[n] = __builtin_bit_cast(f16x8, *(const u32x4*)&Bs[rr * 128 + (ko ^ ((rr & 7) * 8))]);
    }
#pragma unroll
    for (int m = 0; m < 8; ++m)
#pragma unroll
      for (int n = 0; n < 4; ++n)
        acc[m][n] = __builtin_amdgcn_mfma_f32_16x16x32_f16(af[m], bg[n], acc[m][n], 0, 0, 0);
  }
  const int lq4 = (lane >> 4) * 4;
  const int chunk = blockIdx.x * 2 + (wave >> 2);   // 16 row-chunks of 128 per batch
#pragma unroll
  for (int nf = 0; nf < 4; ++nf) {
    const int col = col0 + wc + nf * 16 + lr;
    float mx = -3.0e38f;
#pragma unroll
    for (int mf = 0; mf < 8; ++mf) {
#pragma unroll
      for (int r = 0; r < 4; ++r) {
        const int row = row0 + wr + mf * 16 + lq4 + r;
        u16 hq = f2h(acc[mf][nf][r]);
        STb[(size_t)row * NN + col] = hq;
        mx = fmaxf(mx, h2f(hq));
      }
    }
    mx = fmaxf(mx, __shfl_xor(mx, 16));
    mx = fmaxf(mx, __shfl_xor(mx, 32));
    float s = 0.0f;
#pragma unroll
    for (int mf = 0; mf < 8; ++mf)
#pragma unroll
      for (int r = 0; r < 4; ++r)
        s += __expf(h2f(f2h(acc[mf][nf][r])) - mx);
    s += __shfl_xor(s, 16);
    s += __shfl_xor(s, 32);
    if (lane < 16) {
      size_t idx = (size_t)chunk * MTOT + (size_t)bz * NN + col;
      Mpart[idx] = mx;
      Zpart[idx] = s;
    }
  }
}

// combine 16 chunk partials: M = max, Z = sum exp(Mc-M)*Zc
__global__ void mzreduce(const float* __restrict__ Mpart, const float* __restrict__ Zpart,
                         float* __restrict__ Mrow, float* __restrict__ Zrow) {
  int i = blockIdx.x * 256 + threadIdx.x;   // 16384
  float M = Mpart[i];
#pragma unroll
  for (int c = 1; c < 16; ++c) M = fmaxf(M, Mpart[(size_t)c * MTOT + i]);
  float Z = 0.0f;
#pragma unroll
  for (int c = 0; c < 16; ++c)
    Z += __expf(Mpart[(size_t)c * MTOT + i] - M) * Zpart[(size_t)c * MTOT + i];
  Mrow[i] = M;
  Zrow[i] = Z;
}

// ---------------- fused PV GEMM: out[n][d] = sum_m exp(ST[n][m]-M[m]) * X3T'[d][m] + Xb[n][d]
__global__ __launch_bounds__(256)
void gemm_pv(const u16* __restrict__ ST, const float* __restrict__ Mrow,
             const u16* __restrict__ X3T, const u16* __restrict__ Xb,
             float* __restrict__ out) {
  const int bz = blockIdx.z;
  const u16* Sb = ST + (size_t)bz * NN * NN;
  const u16* Bb = X3T + (size_t)bz * (size_t)ND * NN;
  const float* Mb = Mrow + bz * NN;
  const int row0 = blockIdx.x * 64;        // n tile
  const int col0 = blockIdx.y * 128;       // d tile
  __shared__ __attribute__((aligned(16))) u16 As[64 * 64];
  __shared__ __attribute__((aligned(16))) u16 Bs[128 * 64];
  const int tid = threadIdx.x, lane = tid & 63, wave = tid >> 6;
  const int wr = (wave >> 1) * 32, wc = (wave & 1) * 64;
  const int lr = lane & 15, lk8 = (lane >> 4) * 8;
  const int arow = tid >> 3;               // 0..31
  const int akc  = (tid & 7) * 8;          // 0..56
  f32x4 acc[2][4] = {};
  for (int kt = 0; kt < NN; kt += 64) {
    // B (X3T rows d, k=m contiguous) async direct-to-LDS
#pragma unroll
    for (int i = 0; i < 4; ++i) {
      int e = i * 256 + tid;
      int r = e >> 3, kc = (e & 7) * 8;
      gld_lds16(Bb + (size_t)(col0 + r) * NN + kt + kc, Bs + e * 8);
    }
    // A = exp(ST - M[m]) reg-staged; m contiguous -> vector ds_write_b128
    U8 s0, s1, p0, p1;
    s0.v = *(const u32x4*)&Sb[(size_t)(row0 + arow) * NN + kt + akc];
    s1.v = *(const u32x4*)&Sb[(size_t)(row0 + arow + 32) * NN + kt + akc];
    float4 M0 = *(const float4*)&Mb[kt + akc];
    float4 M1 = *(const float4*)&Mb[kt + akc + 4];
    p0.h[0] = f2h(__expf(h2f(s0.h[0]) - M0.x));
    p0.h[1] = f2h(__expf(h2f(s0.h[1]) - M0.y));
    p0.h[2] = f2h(__expf(h2f(s0.h[2]) - M0.z));
    p0.h[3] = f2h(__expf(h2f(s0.h[3]) - M0.w));
    p0.h[4] = f2h(__expf(h2f(s0.h[4]) - M1.x));
    p0.h[5] = f2h(__expf(h2f(s0.h[5]) - M1.y));
    p0.h[6] = f2h(__expf(h2f(s0.h[6]) - M1.z));
    p0.h[7] = f2h(__expf(h2f(s0.h[7]) - M1.w));
    p1.h[0] = f2h(__expf(h2f(s1.h[0]) - M0.x));
    p1.h[1] = f2h(__expf(h2f(s1.h[1]) - M0.y));
    p1.h[2] = f2h(__expf(h2f(s1.h[2]) - M0.z));
    p1.h[3] = f2h(__expf(h2f(s1.h[3]) - M0.w));
    p1.h[4] = f2h(__expf(h2f(s1.h[4]) - M1.x));
    p1.h[5] = f2h(__expf(h2f(s1.h[5]) - M1.y));
    p1.h[6] = f2h(__expf(h2f(s1.h[6]) - M1.z));
    p1.h[7] = f2h(__expf(h2f(s1.h[7]) - M1.w));
    *(u32x4*)&As[arow * 64 + akc] = p0.v;
    *(u32x4*)&As[(arow + 32) * 64 + akc] = p1.v;
    __syncthreads();
#pragma unroll
    for (int kk = 0; kk < 2; ++kk) {
      f16x8 af[2], bg[4];
      const int ko = kk * 32 + lk8;
#pragma unroll
      for (int m = 0; m < 2; ++m)
        af[m] = __builtin_bit_cast(f16x8, *(const u32x4*)&As[(wr + m * 16 + lr) * 64 + ko]);
#pragma unroll
      for (int n = 0; n < 4; ++n)
        bg[n] = __builtin_bit_cast(f16x8, *(const u32x4*)&Bs[(wc + n * 16 + lr) * 64 + ko]);
#pragma unroll
      for (int m = 0; m < 2; ++m)
#pragma unroll
        for (int n = 0; n < 4; ++n)
          acc[m][n] = __builtin_amdgcn_mfma_f32_16x16x32_f16(af[m], bg[n], acc[m][n], 0, 0, 0);
    }
    __syncthreads();
  }
  const int lq4 = (lane >> 4) * 4;
#pragma unroll
  for (int m = 0; m < 2; ++m) {
#pragma unroll
    for (int n = 0; n < 4; ++n) {
      const int col = col0 + wc + n * 16 + lr;
#pragma unroll
      for (int r = 0; r < 4; ++r) {
        const int row = row0 + wr + m * 16 + lq4 + r;
        float v = acc[m][n][r] + h2f(Xb[((size_t)bz * NN + row) * ND + col]);
        out[((size_t)bz * NN + row) * (size_t)ND + col] = v;
      }
    }
  }
}

// ---------------- BatchNorm stats / apply (Y in fp16) ----------------

__global__ void bn_stats(const u16* __restrict__ Yh, float* __restrict__ sums) {
  int t = threadIdx.x;                       // 0..191
  const ushort4* p = (const ushort4*)Yh + (size_t)blockIdx.x * 128 * 192 + t;
  float s0 = 0, s1 = 0, s2 = 0, s3 = 0, q0 = 0, q1 = 0, q2 = 0, q3 = 0;
  for (int r = 0; r < 128; ++r) {
    ushort4 v = p[(size_t)r * 192];
    float a = h2f(v.x), b = h2f(v.y), c = h2f(v.z), d = h2f(v.w);
    s0 += a; s1 += b; s2 += c; s3 += d;
    q0 += a * a; q1 += b * b; q2 += c * c; q3 += d * d;
  }
  int c = t * 4;
  atomicAdd(&sums[c + 0], s0); atomicAdd(&sums[c + 1], s1);
  atomicAdd(&sums[c + 2], s2); atomicAdd(&sums[c + 3], s3);
  atomicAdd(&sums[CCH + c + 0], q0); atomicAdd(&sums[CCH + c + 1], q1);
  atomicAdd(&sums[CCH + c + 2], q2); atomicAdd(&sums[CCH + c + 3], q3);
}

__global__ void bn_finalize(const float* __restrict__ sums,
                            const float* __restrict__ g1, const float* __restrict__ be1,
                            const float* __restrict__ g2, const float* __restrict__ be2,
                            const float* __restrict__ g3, const float* __restrict__ be3,
                            float* __restrict__ scale, float* __restrict__ shift) {
  int c = blockIdx.x * 256 + threadIdx.x;
  if (c >= CCH) return;
  const float inv = 1.0f / (float)MTOT;
  float mu  = sums[c] * inv;
  float var = sums[CCH + c] * inv - mu * mu;
  float g, be;
  if (c < 128)      { g = g1[c];       be = be1[c]; }
  else if (c < 256) { g = g2[c - 128]; be = be2[c - 128]; }
  else              { g = g3[c - 256]; be = be3[c - 256]; }
  float sc = rsqrtf(var + 1e-5f) * g;
  scale[c] = sc;
  shift[c] = be - mu * sc;
}

__global__ void bn_apply_route(const u16* __restrict__ Yh, const float* __restrict__ scale,
                               const float* __restrict__ shift, u16* __restrict__ X1b,
                               u16* __restrict__ X2b, u16* __restrict__ X3b) {
  size_t idx4 = (size_t)blockIdx.x * 256 + threadIdx.x;   // 16384*192 total
  int row = (int)(idx4 / 192);
  int c4  = (int)(idx4 % 192);
  int c   = c4 * 4;
  ushort4 y = ((const ushort4*)Yh)[idx4];
  float4 sc = ((const float4*)scale)[c4];
  float4 sh = ((const float4*)shift)[c4];
  ushort4 o;
  o.x = f2h(h2f(y.x) * sc.x + sh.x);
  o.y = f2h(h2f(y.y) * sc.y + sh.y);
  o.z = f2h(h2f(y.z) * sc.z + sh.z);
  o.w = f2h(h2f(y.w) * sc.w + sh.w);
  if (c < 128)      *(ushort4*)&X1b[(size_t)row * 128 + c] = o;
  else if (c < 256) *(ushort4*)&X2b[(size_t)row * 128 + (c - 128)] = o;
  else              *(ushort4*)&X3b[(size_t)row * 512 + (c - 256)] = o;
}

// ---------------- X3 transpose with 1/Z fold ----------------

__global__ void transpose_scale(const u16* __restrict__ in, const float* __restrict__ Zrow,
                                u16* __restrict__ out, int R, int C) {
  // per-batch [R][C] -> [C][R], scaling row m by 1/Zrow[bz*R+m]
  __shared__ u16 tile[64][66];
  int bz = blockIdx.z;
  const u16* ib = in + (size_t)bz * R * C;
  u16* ob = out + (size_t)bz * R * C;
  int r0 = blockIdx.x * 64, c0 = blockIdx.y * 64;
  int t = threadIdx.x, tr = t >> 4, tc4 = (t & 15) * 4;
#pragma unroll
  for (int i = 0; i < 4; ++i) {
    int rl = i * 16 + tr;
    float iz = 1.0f / Zrow[(size_t)bz * R + r0 + rl];
    ushort4 v = *(const ushort4*)&ib[(size_t)(r0 + rl) * C + c0 + tc4];
    tile[tc4 + 0][rl] = f2h(h2f(v.x) * iz);
    tile[tc4 + 1][rl] = f2h(h2f(v.y) * iz);
    tile[tc4 + 2][rl] = f2h(h2f(v.z) * iz);
    tile[tc4 + 3][rl] = f2h(h2f(v.w) * iz);
  }
  __syncthreads();
#pragma unroll
  for (int i = 0; i < 4; ++i) {
    int cl = i * 16 + tr;
    ushort4 o;
    o.x = tile[cl][tc4 + 0]; o.y = tile[cl][tc4 + 1];
    o.z = tile[cl][tc4 + 2]; o.w = tile[cl][tc4 + 3];
    *(ushort4*)&ob[(size_t)(c0 + cl) * R + r0 + tc4] = o;
  }
}

// ---------------- launch ----------------

extern "C" void kernel_launch(void* const* d_in, const int* in_sizes, int n_in,
                              void* d_out, int out_size, void* d_ws, size_t ws_size,
                              hipStream_t stream) {
  const float* X   = (const float*)d_in[0];
  const float* W1  = (const float*)d_in[1];
  const float* b1  = (const float*)d_in[2];
  const float* g1  = (const float*)d_in[3];
  const float* be1 = (const float*)d_in[4];
  const float* W2  = (const float*)d_in[5];
  const float* b2  = (const float*)d_in[6];
  const float* g2  = (const float*)d_in[7];
  const float* be2 = (const float*)d_in[8];
  const float* W3  = (const float*)d_in[9];
  const float* b3  = (const float*)d_in[10];
  const float* g3  = (const float*)d_in[11];
  const float* be3 = (const float*)d_in[12];
  float* out = (float*)d_out;

  char* ws = (char*)d_ws;
  // small region
  float* sums  = (float*)ws;                 // 1536
  float* scale = sums + 1536;                // 768
  float* shift = scale + 768;                // 768
  float* bcat  = shift + 768;                // 768
  float* Mrow  = bcat + 768;                 // 16384
  float* Zrow  = Mrow + 16384;               // 16384
  float* Mpart = Zrow + 16384;               // 16*16384
  float* Zpart = Mpart + 16 * 16384;         // 16*16384
  size_t off = (size_t)(1536 + 768 + 768 + 768 + 16384 + 16384 + 32 * 16384) * 4;
  // persistent fp16 region
  u16* X1b = (u16*)(ws + off); off += (size_t)MTOT * 128 * 2;
  u16* X2b = (u16*)(ws + off); off += (size_t)MTOT * 128 * 2;
  u16* X3b = (u16*)(ws + off); off += (size_t)MTOT * 512 * 2;
  u16* X3T = (u16*)(ws + off); off += (size_t)MTOT * 512 * 2;
  u16* Xb  = (u16*)(ws + off); off += (size_t)MTOT * 512 * 2;
  // union region: {Wcat, Yh} (dead before ST is written) overlaid with fp16 ST
  char* uni = ws + off;
  u16* Wcat = (u16*)uni;                               // 768 KB
  u16* Yh   = (u16*)(uni + 768 * 512 * 2);             // 24 MB fp16
  u16* ST   = (u16*)uni;                               // 64 MB fp16
  size_t total = off + (size_t)NB * NN * NN * 2;
  if (ws_size < total) return;  // workspace too small: fail visibly

  hipMemsetAsync(sums, 0, 1536 * sizeof(float), stream);

  cvt_f32_f16<<<8192, 256, 0, stream>>>(X, Xb, (size_t)MTOT * 512 / 4);
  assemble_w<<<384, 256, 0, stream>>>(W1, W2, W3, b1, b2, b3, Wcat, bcat);

  // proj GEMM: Yh[16384][768] = fp16(leaky(Xb @ Wcat^T + bcat))
  gemm_bt<EPI_BIAS_LEAKY, 128, 128, true><<<dim3(128, 6, 1), 256, 0, stream>>>(
      Xb, Wcat, Yh, CCH, 512, 0, 0, 0, bcat);

  bn_stats<<<128, 192, 0, stream>>>(Yh, sums);
  bn_finalize<<<3, 256, 0, stream>>>(sums, g1, be1, g2, be2, g3, be3, scale, shift);
  bn_apply_route<<<12288, 256, 0, stream>>>(Yh, scale, shift, X1b, X2b, X3b);

  // ST[b][n][m] = fp16(X1[b,n] . X2[b,m]) one-shot + col-max/Z partials
  gemm_s<<<dim3(8, 8, 8), 512, 0, stream>>>(X1b, X2b, ST, Mpart, Zpart);
  mzreduce<<<64, 256, 0, stream>>>(Mpart, Zpart, Mrow, Zrow);

  // X3T[d][m] = fp16(X3[m][d] / Z[m])
  transpose_scale<<<dim3(32, 8, 8), 256, 0, stream>>>(X3b, Zrow, X3T, 2048, 512);

  // out[b][n][d] = sum_m exp(ST[n][m]-M[m]) * X3T[d][m] + Xb[n][d]
  gemm_pv<<<dim3(32, 4, 8), 256, 0, stream>>>(ST, Mrow, X3T, Xb, out);
}